// Round 4
// baseline (466.035 us; speedup 1.0000x reference)
//
#include <hip/hip_runtime.h>

// Per-channel bilinear translation of [B,C,H,W] f32 grid.
// Horizontal shift = wave-uniform quad shift s=D>>2 + uniform remainder r=D&3:
// each lane loads aligned float4s at quad (lane+s) and (lane+s+1) directly
// (coalesced, overlapping cache lines -> L1). No LDS, no shuffles.
// 2 output rows (same channel) per iteration share D/s/r and fx weights;
// contiguous 16-pair chunks per wave make overlapping input rows L1-hot.
constexpr int Bn = 8, Cn = 128, Hn = 256, Wn = 256;
constexpr int NROWS  = Bn * Cn * Hn;
constexpr int NPAIRS = NROWS / 2;    // 131072

__global__ __launch_bounds__(256) void convection_kernel(
    const float* __restrict__ in, const float* __restrict__ cvec, float* __restrict__ out)
{
    const int lane = threadIdx.x & 63;
    int wave = (int)blockIdx.x * (blockDim.x >> 6) + (threadIdx.x >> 6);
    wave = __builtin_amdgcn_readfirstlane(wave);
    const int nWaves = (int)gridDim.x * (blockDim.x >> 6);
    const int chunk  = (NPAIRS + nWaves - 1) / nWaves;      // 16 with grid=2048
    const int pBeg   = wave * chunk;
    const int pEnd   = (pBeg + chunk < NPAIRS) ? pBeg + chunk : NPAIRS;

    for (int p = pBeg; p < pEnd; ++p) {
        const int h0    = (p & 127) << 1;                   // first row of pair
        const int plIdx = p >> 7;                           // b*C + ch
        const int ch    = plIdx & (Cn - 1);
        const float cy  = cvec[2 * ch];
        const float cx  = cvec[2 * ch + 1];
        const float* plane = in + ((long long)plIdx << 16);

        // ---- horizontal setup (shared by both rows; wave-uniform) ----
        const float ncx = fminf(fmaxf(-cx, -600.f), 600.f); // guard int cast
        const int D = (int)floorf(ncx);
        const int s = D >> 2;                               // arithmetic shift = floor div
        const int r = D & 3;
        int q0 = lane + s;     q0 = q0 < 0 ? 0 : (q0 > 63 ? 63 : q0);
        int q1 = lane + s + 1; q1 = q1 < 0 ? 0 : (q1 > 63 ? 63 : q1);
        // clamped-quad garbage is always weight-masked (true index OOB there)

        // ---- vertical setup per row: reference-exact f32 per-element ----
        const float posya = (float)h0 - cy;
        const float y0fa  = floorf(posya);
        const float wya   = posya - y0fa;
        const int   y0a   = (int)fminf(fmaxf(y0fa, -600.f), 600.f);
        const bool  va0   = (unsigned)y0a       < (unsigned)Hn;
        const bool  va1   = (unsigned)(y0a + 1) < (unsigned)Hn;
        const float fa0   = va0 ? (1.0f - wya) : 0.0f;      // zero-pad folded in
        const float fa1   = va1 ? wya          : 0.0f;
        const float* pA   = plane + ((va0 ? y0a     : 0) << 8);
        const float* pB   = plane + ((va1 ? y0a + 1 : 0) << 8);

        const float posyb = (float)(h0 + 1) - cy;
        const float y0fb  = floorf(posyb);
        const float wyb   = posyb - y0fb;
        const int   y0b   = (int)fminf(fmaxf(y0fb, -600.f), 600.f);
        const bool  vb0   = (unsigned)y0b       < (unsigned)Hn;
        const bool  vb1   = (unsigned)(y0b + 1) < (unsigned)Hn;
        const float fb0   = vb0 ? (1.0f - wyb) : 0.0f;
        const float fb1   = vb1 ? wyb          : 0.0f;
        const float* pC   = plane + ((vb0 ? y0b     : 0) << 8);
        const float* pD   = plane + ((vb1 ? y0b + 1 : 0) << 8);

        // ---- 8 coalesced float4 loads, all issued up-front (8-deep MLP) ----
        const float4 A0 = *(const float4*)(pA + 4 * q0);
        const float4 A1 = *(const float4*)(pA + 4 * q1);
        const float4 B0 = *(const float4*)(pB + 4 * q0);
        const float4 B1 = *(const float4*)(pB + 4 * q1);
        const float4 C0 = *(const float4*)(pC + 4 * q0);
        const float4 C1 = *(const float4*)(pC + 4 * q1);
        const float4 D0 = *(const float4*)(pD + 4 * q0);
        const float4 D1 = *(const float4*)(pD + 4 * q1);

        // ---- vertical lerp into 8-wide windows (matches reference order) ----
        float ua[8], ub[8];
        ua[0] = fa0*A0.x + fa1*B0.x;  ua[1] = fa0*A0.y + fa1*B0.y;
        ua[2] = fa0*A0.z + fa1*B0.z;  ua[3] = fa0*A0.w + fa1*B0.w;
        ua[4] = fa0*A1.x + fa1*B1.x;  ua[5] = fa0*A1.y + fa1*B1.y;
        ua[6] = fa0*A1.z + fa1*B1.z;  ua[7] = fa0*A1.w + fa1*B1.w;
        ub[0] = fb0*C0.x + fb1*D0.x;  ub[1] = fb0*C0.y + fb1*D0.y;
        ub[2] = fb0*C0.z + fb1*D0.z;  ub[3] = fb0*C0.w + fb1*D0.w;
        ub[4] = fb0*C1.x + fb1*D1.x;  ub[5] = fb0*C1.y + fb1*D1.y;
        ub[6] = fb0*C1.z + fb1*D1.z;  ub[7] = fb0*C1.w + fb1*D1.w;

        // ---- window select: wave-uniform r, static indices only (no scratch) ----
        float wa0, wa1, wa2, wa3, wa4, wb0, wb1, wb2, wb3, wb4;
        switch (r) {
            case 0:
                wa0=ua[0]; wa1=ua[1]; wa2=ua[2]; wa3=ua[3]; wa4=ua[4];
                wb0=ub[0]; wb1=ub[1]; wb2=ub[2]; wb3=ub[3]; wb4=ub[4]; break;
            case 1:
                wa0=ua[1]; wa1=ua[2]; wa2=ua[3]; wa3=ua[4]; wa4=ua[5];
                wb0=ub[1]; wb1=ub[2]; wb2=ub[3]; wb3=ub[4]; wb4=ub[5]; break;
            case 2:
                wa0=ua[2]; wa1=ua[3]; wa2=ua[4]; wa3=ua[5]; wa4=ua[6];
                wb0=ub[2]; wb1=ub[3]; wb2=ub[4]; wb3=ub[5]; wb4=ub[6]; break;
            default:
                wa0=ua[3]; wa1=ua[4]; wa2=ua[5]; wa3=ua[6]; wa4=ua[7];
                wb0=ub[3]; wb1=ub[4]; wb2=ub[5]; wb3=ub[6]; wb4=ub[7]; break;
        }

        // ---- horizontal weights (shared by both rows; per-lane) ----
        float fx0[4], fx1[4];
        const int e0b = 4 * lane + D;
        #pragma unroll
        for (int j = 0; j < 4; ++j) {
            const float posx = (float)(4 * lane + j) - cx;  // reference's exact pos_x
            const int   e0   = e0b + j;
            const float wx   = posx - (float)e0;            // drift case -> wx==1.0 exactly
            fx0[j] = ((unsigned)e0       < (unsigned)Wn) ? (1.0f - wx) : 0.0f;
            fx1[j] = ((unsigned)(e0 + 1) < (unsigned)Wn) ? wx          : 0.0f;
        }

        float4 oa, ob;
        oa.x = fx0[0]*wa0 + fx1[0]*wa1;  oa.y = fx0[1]*wa1 + fx1[1]*wa2;
        oa.z = fx0[2]*wa2 + fx1[2]*wa3;  oa.w = fx0[3]*wa3 + fx1[3]*wa4;
        ob.x = fx0[0]*wb0 + fx1[0]*wb1;  ob.y = fx0[1]*wb1 + fx1[1]*wb2;
        ob.z = fx0[2]*wb2 + fx1[2]*wb3;  ob.w = fx0[3]*wb3 + fx1[3]*wb4;

        float* orow = out + ((long long)plIdx << 16) + (h0 << 8) + 4 * lane;
        *(float4*)(orow)       = oa;                        // coalesced 1KB/instr
        *(float4*)(orow + 256) = ob;
    }
}

extern "C" void kernel_launch(void* const* d_in, const int* in_sizes, int n_in,
                              void* d_out, int out_size, void* d_ws, size_t ws_size,
                              hipStream_t stream) {
    const float* in = (const float*)d_in[0];
    const float* c  = (const float*)d_in[1];
    float* out      = (float*)d_out;

    dim3 block(256);
    dim3 grid(2048);   // 8192 waves -> 16 contiguous row-pairs per wave
    hipLaunchKernelGGL(convection_kernel, grid, block, 0, stream, in, c, out);
}

// Round 8
// 441.243 us; speedup vs baseline: 1.0562x; 1.0562x over previous
//
#include <hip/hip_runtime.h>

// Per-channel bilinear translation of [B,C,H,W] f32 grid — register-carried rows.
// Each wave owns 32 consecutive rows of ONE plane (b,ch): all per-channel params
// (D=floor(-cx), quad shift s=D>>2, remainder r=D&3, fx weights) are loop-invariant.
// Input rows are loaded ONCE each (1 coalesced float4 load/row), shifted into a
// 5-element per-lane window via 8 __shfl, and carried in registers: output row h
// needs windows of input rows y0(h), y0(h)+1, and y0 advances by exactly +1 per
// row except rare float-rounding drift (handled by a wave-uniform slow path).
// Issue traffic: 1 load + 1 store per 1KB row (vs 10 vmem/2 rows in round 4).
constexpr int Cn = 128, Hn = 256, Wn = 256;

__global__ __launch_bounds__(256) void convection_kernel(
    const float* __restrict__ in, const float* __restrict__ cvec, float* __restrict__ out)
{
    const int lane  = threadIdx.x & 63;
    const int wave  = (int)blockIdx.x * 4 + (threadIdx.x >> 6);
    const int plane = wave >> 3;                 // b*C + ch  (8 waves per plane)
    const int h0    = (wave & 7) << 5;           // 32 rows per wave
    const int ch    = plane & (Cn - 1);

    const float cy = cvec[2 * ch];
    const float cx = cvec[2 * ch + 1];
    const float* __restrict__ pin = in  + ((long long)plane << 16);
    float* __restrict__ pout      = out + ((long long)plane << 16);

    // ---- loop-invariant horizontal setup (wave-uniform except fx) ----
    const float ncx = fminf(fmaxf(-cx, -600.f), 600.f);  // guard int cast
    const int D = (int)floorf(ncx);
    const int s = D >> 2;                        // arithmetic shift = floor div
    const int r = D & 3;
    int q0 = lane + s;     q0 = q0 < 0 ? 0 : (q0 > 63 ? 63 : q0);
    int q1 = lane + s + 1; q1 = q1 < 0 ? 0 : (q1 > 63 ? 63 : q1);
    // clamped-quad garbage is always weight-masked (true column OOB there)

    float fx0[4], fx1[4];
    #pragma unroll
    for (int j = 0; j < 4; ++j) {
        const int   col  = 4 * lane + j;
        const float posx = (float)col - cx;      // reference's exact f32 pos_x
        const int   e0   = col + D;
        const float wx   = posx - (float)e0;     // drift case -> wx == 1.0 exactly
        fx0[j] = ((unsigned)e0       < (unsigned)Wn) ? (1.0f - wx) : 0.0f;
        fx1[j] = ((unsigned)(e0 + 1) < (unsigned)Wn) ? wx          : 0.0f;
    }

    // shifted 5-element window from a natural-layout row (lane holds quad `lane`)
    auto mkwin = [&](const float4 g, float* w) {
        const float u0 = __shfl(g.x, q0), u1 = __shfl(g.y, q0),
                    u2 = __shfl(g.z, q0), u3 = __shfl(g.w, q0);
        const float u4 = __shfl(g.x, q1), u5 = __shfl(g.y, q1),
                    u6 = __shfl(g.z, q1), u7 = __shfl(g.w, q1);
        switch (r) {                             // wave-uniform -> scalar branch
            case 0:  w[0]=u0; w[1]=u1; w[2]=u2; w[3]=u3; w[4]=u4; break;
            case 1:  w[0]=u1; w[1]=u2; w[2]=u3; w[3]=u4; w[4]=u5; break;
            case 2:  w[0]=u2; w[1]=u3; w[2]=u4; w[3]=u5; w[4]=u6; break;
            default: w[0]=u3; w[1]=u4; w[2]=u5; w[3]=u6; w[4]=u7; break;
        }
    };
    // reference-exact floor of (h - cy), clamped for safe int use
    auto y0of = [&](int h) -> int {
        const float p = (float)h - cy;
        const float f = floorf(p);
        return (int)fminf(fmaxf(f, -600.f), 600.f);
    };

    // ---- prologue: windows for rows y0(h0), y0(h0)+1 ----
    int y0c = y0of(h0);
    const int rA = min(max(y0c,     0), 255);
    const int rB = min(max(y0c + 1, 0), 255);
    const float4 A = *(const float4*)(pin + (rA << 8) + 4 * lane);
    const float4 B = *(const float4*)(pin + (rB << 8) + 4 * lane);
    float w0[5], w1[5], wn[5];
    mkwin(A, w0); mkwin(B, w1);

    for (int h = h0; h < h0 + 32; ++h) {
        // prefetch: G is row y0(h+1)+1 — needed by BOTH fast and slow advance paths
        const int y0n = y0of(h + 1);
        const int rG  = min(max(y0n + 1, 0), 255);
        const float4 G = *(const float4*)(pin + (rG << 8) + 4 * lane);

        // ---- output row h: vertical lerp on the 5-window, then horizontal ----
        const float posy = (float)h - cy;
        const float wy   = posy - (float)y0c;    // y0c == floorf(posy) exactly
        const float f0   = ((unsigned)y0c       < (unsigned)Hn) ? (1.0f - wy) : 0.0f;
        const float f1   = ((unsigned)(y0c + 1) < (unsigned)Hn) ? wy          : 0.0f;
        const float xh0 = f0*w0[0] + f1*w1[0];
        const float xh1 = f0*w0[1] + f1*w1[1];
        const float xh2 = f0*w0[2] + f1*w1[2];
        const float xh3 = f0*w0[3] + f1*w1[3];
        const float xh4 = f0*w0[4] + f1*w1[4];
        float4 o;
        o.x = fx0[0]*xh0 + fx1[0]*xh1;
        o.y = fx0[1]*xh1 + fx1[1]*xh2;
        o.z = fx0[2]*xh2 + fx1[2]*xh3;
        o.w = fx0[3]*xh3 + fx1[3]*xh4;
        *(float4*)(pout + (h << 8) + 4 * lane) = o;   // coalesced 1KB/instr

        // ---- advance the carried windows (wave-uniform branch) ----
        const int dk = __builtin_amdgcn_readfirstlane(y0n - y0c);
        if (dk == 1) {                            // common: shift chain by one row
            mkwin(G, wn);
            #pragma unroll
            for (int i = 0; i < 5; ++i) { w0[i] = w1[i]; w1[i] = wn[i]; }
        } else if (dk != 0) {                     // rare rounding drift: rebuild both
            const int rN = min(max(y0n, 0), 255);
            const float4 N = *(const float4*)(pin + (rN << 8) + 4 * lane);
            mkwin(N, w0);
            mkwin(G, w1);
        }                                         // dk==0: windows unchanged
        y0c = y0n;
    }
}

extern "C" void kernel_launch(void* const* d_in, const int* in_sizes, int n_in,
                              void* d_out, int out_size, void* d_ws, size_t ws_size,
                              hipStream_t stream) {
    const float* in = (const float*)d_in[0];
    const float* c  = (const float*)d_in[1];
    float* out      = (float*)d_out;

    dim3 block(256);
    dim3 grid(2048);   // 8192 waves = 8 per plane, 32 consecutive rows each
    hipLaunchKernelGGL(convection_kernel, grid, block, 0, stream, in, c, out);
}

// Round 9
// 436.123 us; speedup vs baseline: 1.0686x; 1.0117x over previous
//
#include <hip/hip_runtime.h>

// Per-channel bilinear translation of [B,C,H,W] f32 grid — group-of-8 batched loads.
// R8 finding: per-row structures expose ~900cy HBM latency per row (R3: no prefetch,
// R8: 1-deep prefetch -> both ~140us; extra VALU was free => latency-bound).
// Fix: per group of 8 output rows, issue 9 independent row loads up-front (9-deep
// MLP, incremental vmcnt drain), then 9 window-builds + 8 lerp/store. y0 advances
// by exactly +1 per row (wave-uniform check); drift groups take a generic slow path.
constexpr int Cn = 128, Hn = 256, Wn = 256;

__global__ __launch_bounds__(256) void convection_kernel(
    const float* __restrict__ in, const float* __restrict__ cvec, float* __restrict__ out)
{
    const int lane  = threadIdx.x & 63;
    const int wave  = (int)blockIdx.x * 4 + (threadIdx.x >> 6);
    const int plane = wave >> 3;                 // b*C + ch  (8 waves per plane)
    const int h0    = (wave & 7) << 5;           // 32 rows per wave
    const int ch    = plane & (Cn - 1);

    const float cy = cvec[2 * ch];
    const float cx = cvec[2 * ch + 1];
    const float* __restrict__ pin = in  + ((long long)plane << 16);
    float* __restrict__ pout      = out + ((long long)plane << 16);

    // ---- loop-invariant horizontal setup (wave-uniform except fx) ----
    const float ncx = fminf(fmaxf(-cx, -600.f), 600.f);  // guard int cast
    const int D = (int)floorf(ncx);
    const int s = D >> 2;                        // arithmetic shift = floor div
    const int r = D & 3;
    int q0 = lane + s;     q0 = q0 < 0 ? 0 : (q0 > 63 ? 63 : q0);
    int q1 = lane + s + 1; q1 = q1 < 0 ? 0 : (q1 > 63 ? 63 : q1);
    // clamped-quad garbage is always weight-masked (true column OOB there)

    float fx0[4], fx1[4];
    #pragma unroll
    for (int j = 0; j < 4; ++j) {
        const int   col  = 4 * lane + j;
        const float posx = (float)col - cx;      // reference's exact f32 pos_x
        const int   e0   = col + D;
        const float wx   = posx - (float)e0;     // drift case -> wx == 1.0 exactly
        fx0[j] = ((unsigned)e0       < (unsigned)Wn) ? (1.0f - wx) : 0.0f;
        fx1[j] = ((unsigned)(e0 + 1) < (unsigned)Wn) ? wx          : 0.0f;
    }

    // shifted 5-element window from a natural-layout row (lane holds quad `lane`)
    auto mkwin = [&](const float4 g, float (&w)[5]) {
        const float u0 = __shfl(g.x, q0), u1 = __shfl(g.y, q0),
                    u2 = __shfl(g.z, q0), u3 = __shfl(g.w, q0);
        const float u4 = __shfl(g.x, q1), u5 = __shfl(g.y, q1),
                    u6 = __shfl(g.z, q1), u7 = __shfl(g.w, q1);
        switch (r) {                             // wave-uniform -> scalar branch
            case 0:  w[0]=u0; w[1]=u1; w[2]=u2; w[3]=u3; w[4]=u4; break;
            case 1:  w[0]=u1; w[1]=u2; w[2]=u3; w[3]=u4; w[4]=u5; break;
            case 2:  w[0]=u2; w[1]=u3; w[2]=u4; w[3]=u5; w[4]=u6; break;
            default: w[0]=u3; w[1]=u4; w[2]=u5; w[3]=u6; w[4]=u7; break;
        }
    };
    // reference-exact floor of (h - cy), clamped for safe int use
    auto y0of = [&](int h) -> int {
        const float p = (float)h - cy;
        const float f = floorf(p);
        return (int)fminf(fmaxf(f, -600.f), 600.f);
    };
    auto clampRow = [](int v) -> int { return v < 0 ? 0 : (v > Hn - 1 ? Hn - 1 : v); };

    for (int g = 0; g < 4; ++g) {
        const int hg  = h0 + 8 * g;
        const int y00 = y0of(hg);

        // wave-uniform monotonicity check: y0(hg+j) == y00 + j for all j
        bool mono = true;
        #pragma unroll
        for (int j = 1; j < 8; ++j) mono = mono && (y0of(hg + j) == y00 + j);

        if (mono) {
            // ---- fast path: 9 independent row loads issued up-front ----
            float4 R[9];
            #pragma unroll
            for (int i = 0; i < 9; ++i)
                R[i] = *(const float4*)(pin + (clampRow(y00 + i) << 8) + 4 * lane);

            float W[9][5];                       // fully unrolled -> static idx -> regs
            #pragma unroll
            for (int i = 0; i < 9; ++i) mkwin(R[i], W[i]);

            #pragma unroll
            for (int j = 0; j < 8; ++j) {
                const int   h    = hg + j;
                const int   y0   = y00 + j;
                const float posy = (float)h - cy;
                const float wy   = posy - (float)y0;   // y0 == floorf(posy) exactly
                const float f0   = ((unsigned)y0       < (unsigned)Hn) ? (1.0f - wy) : 0.0f;
                const float f1   = ((unsigned)(y0 + 1) < (unsigned)Hn) ? wy          : 0.0f;
                const float xh0 = f0*W[j][0] + f1*W[j+1][0];
                const float xh1 = f0*W[j][1] + f1*W[j+1][1];
                const float xh2 = f0*W[j][2] + f1*W[j+1][2];
                const float xh3 = f0*W[j][3] + f1*W[j+1][3];
                const float xh4 = f0*W[j][4] + f1*W[j+1][4];
                float4 o;
                o.x = fx0[0]*xh0 + fx1[0]*xh1;
                o.y = fx0[1]*xh1 + fx1[1]*xh2;
                o.z = fx0[2]*xh2 + fx1[2]*xh3;
                o.w = fx0[3]*xh3 + fx1[3]*xh4;
                *(float4*)(pout + (h << 8) + 4 * lane) = o;   // coalesced 1KB/instr
            }
        } else {
            // ---- slow path (rare rounding drift / huge cy): generic per row ----
            for (int j = 0; j < 8; ++j) {
                const int   h    = hg + j;
                const int   y0   = y0of(h);
                const float posy = (float)h - cy;
                const float wy   = posy - (float)y0;
                const float f0   = ((unsigned)y0       < (unsigned)Hn) ? (1.0f - wy) : 0.0f;
                const float f1   = ((unsigned)(y0 + 1) < (unsigned)Hn) ? wy          : 0.0f;
                const float4 Ra = *(const float4*)(pin + (clampRow(y0)     << 8) + 4 * lane);
                const float4 Rb = *(const float4*)(pin + (clampRow(y0 + 1) << 8) + 4 * lane);
                float wa[5], wb[5];
                mkwin(Ra, wa); mkwin(Rb, wb);
                const float xh0 = f0*wa[0] + f1*wb[0];
                const float xh1 = f0*wa[1] + f1*wb[1];
                const float xh2 = f0*wa[2] + f1*wb[2];
                const float xh3 = f0*wa[3] + f1*wb[3];
                const float xh4 = f0*wa[4] + f1*wb[4];
                float4 o;
                o.x = fx0[0]*xh0 + fx1[0]*xh1;
                o.y = fx0[1]*xh1 + fx1[1]*xh2;
                o.z = fx0[2]*xh2 + fx1[2]*xh3;
                o.w = fx0[3]*xh3 + fx1[3]*xh4;
                *(float4*)(pout + (h << 8) + 4 * lane) = o;
            }
        }
    }
}

extern "C" void kernel_launch(void* const* d_in, const int* in_sizes, int n_in,
                              void* d_out, int out_size, void* d_ws, size_t ws_size,
                              hipStream_t stream) {
    const float* in = (const float*)d_in[0];
    const float* c  = (const float*)d_in[1];
    float* out      = (float*)d_out;

    dim3 block(256);
    dim3 grid(2048);   // 8192 waves = 8 per plane, 32 rows each (4 groups of 8)
    hipLaunchKernelGGL(convection_kernel, grid, block, 0, stream, in, c, out);
}